// Round 2
// baseline (130.270 us; speedup 1.0000x reference)
//
#include <hip/hip_runtime.h>

// Problem constants (from reference)
#define SEQLEN  128
#define NKV     8
#define BATCH   8
#define HD      128
#define MAXSEQ  4096

constexpr unsigned HD4     = HD / 4;                                  // 32 float4 per head row
constexpr unsigned HALF_F4 = (unsigned)BATCH * NKV * MAXSEQ * HD4;    // 2^23 float4 per tensor
constexpr unsigned NTHREAD = 1u << 19;                                // threads per tensor-half
constexpr int      ITERS   = HALF_F4 / NTHREAD;                       // 16 iterations/thread

// Key invariants (stride = 2^19 float4 = 2^14 rows):
//   e = tid + t*2^19  ->  d4  = e & 31      constant per thread
//                         row = (tid>>5) + t*2^14
//                         s   = row & 4095  constant (t*2^14 rows is a multiple of 4096)
//                         bh  = (tid>>17) + 4*t   exact (no carry into low bits)
// => the window predicate is loop-invariant; the hot path is a pure
//    branch-free strided copy with one 32-bit offset add per iteration.

__global__ __launch_bounds__(256) void kv_update_kernel(
    const float4* __restrict__ xk,     // [SEQLEN][NKV][BATCH][HD]
    const float4* __restrict__ xv,
    const float4* __restrict__ kpast,  // [BATCH][NKV][MAXSEQ][HD]
    const float4* __restrict__ vpast,
    const int*    __restrict__ plen_ptr,
    float4*       __restrict__ out)    // new_k ++ new_v, flat
{
    const unsigned half = blockIdx.x >> 11;              // 0 = K-half, 1 = V-half (uniform)
    const float4* __restrict__ pastp = half ? vpast : kpast;   // SGPR select
    const float4* __restrict__ xnewp = half ? xv : xk;
    float4* __restrict__ o = out + (size_t)half * HALF_F4;

    const unsigned tid = ((blockIdx.x & 2047u) << 8) | threadIdx.x;   // [0, 2^19)
    const int plen = *plen_ptr;

    const unsigned d4   = tid & (HD4 - 1);
    const unsigned row0 = tid >> 5;
    const unsigned s    = row0 & (MAXSEQ - 1);           // loop-invariant
    const unsigned bh0  = row0 >> 12;                    // bh = bh0 + 4t
    const int      sl   = (int)s - plen;

    if ((unsigned)sl < (unsigned)SEQLEN) {
        // window rows (~3% of threads): gather from transposed xk/xv
        // xnew flat f4 index: ((sl*NKV + h)*BATCH + b)*HD4 + d4
        #pragma unroll
        for (int t = 0; t < ITERS; ++t) {
            const unsigned bh = bh0 + 4u * (unsigned)t;
            const unsigned h  = bh & (NKV - 1);
            const unsigned b  = bh >> 3;
            o[tid + ((unsigned)t << 19)] =
                xnewp[(((unsigned)sl * NKV + h) * BATCH + b) * HD4 + d4];
        }
    } else {
        // bulk path: identical flat offset, perfectly coalesced, branch-free
        #pragma unroll
        for (int t = 0; t < ITERS; ++t) {
            const unsigned e = tid + ((unsigned)t << 19);
            o[e] = pastp[e];
        }
    }
}

extern "C" void kernel_launch(void* const* d_in, const int* in_sizes, int n_in,
                              void* d_out, int out_size, void* d_ws, size_t ws_size,
                              hipStream_t stream) {
    const float4* xk    = (const float4*)d_in[0];
    const float4* xv    = (const float4*)d_in[1];
    const float4* kpast = (const float4*)d_in[2];
    const float4* vpast = (const float4*)d_in[3];
    const int*    plen  = (const int*)d_in[4];
    float4*       out   = (float4*)d_out;

    dim3 grid(4096), block(256);   // blocks [0,2048) -> K, [2048,4096) -> V; 16 f4/thread
    kv_update_kernel<<<grid, block, 0, stream>>>(xk, xv, kpast, vpast, plen, out);
}

// Round 3
// 97.028 us; speedup vs baseline: 1.3426x; 1.3426x over previous
//
#include <hip/hip_runtime.h>

// Problem constants (from reference)
#define SEQLEN  128
#define NKV     8
#define BATCH   8
#define HD      128
#define MAXSEQ  4096

typedef float f32x4 __attribute__((ext_vector_type(4)));

constexpr int       HD4     = HD / 4;                                   // 32 float4 per head row
constexpr long long HALF_F4 = (long long)BATCH * NKV * MAXSEQ * HD4;    // 8,388,608 float4 per output tensor

// R1 structure (109.5 us) with exactly ONE change: non-temporal stores on the
// output stream. Out is write-once/never-reread; 'nt' keeps the 537 MB store
// stream from evicting the past caches out of L2/L3, so the ~50% L3 read-hit
// seen in R2's FETCH_SIZE (134 MB vs 268 MB reads) should rise toward ~100%.

__global__ __launch_bounds__(256) void kv_update_kernel(
    const f32x4* __restrict__ xk,     // [SEQLEN][NKV][BATCH][HD]
    const f32x4* __restrict__ xv,
    const f32x4* __restrict__ kpast,  // [BATCH][NKV][MAXSEQ][HD]
    const f32x4* __restrict__ vpast,
    const int*   __restrict__ plen_ptr,
    f32x4*       __restrict__ out)    // new_k ++ new_v, flat
{
    const int plen = *plen_ptr;        // uniform address -> broadcast, cheap
    const long long total  = 2 * HALF_F4;
    const long long stride = (long long)gridDim.x * blockDim.x;

    for (long long i = (long long)blockIdx.x * blockDim.x + threadIdx.x;
         i < total; i += stride) {

        long long rem = i;
        const f32x4* past;
        const f32x4* xnew;
        if (rem >= HALF_F4) { rem -= HALF_F4; past = vpast; xnew = xv; }
        else                {                  past = kpast; xnew = xk; }

        // rem = ((b*NKV + h)*MAXSEQ + s)*HD4 + d4
        const int       d4  = (int)(rem & (HD4 - 1));      // % 32
        const long long row = rem >> 5;                    // / 32
        const int       s   = (int)(row & (MAXSEQ - 1));   // % 4096
        const int       bh  = (int)(row >> 12);            // / 4096
        const int       h   = bh & (NKV - 1);
        const int       b   = bh >> 3;

        const int sl = s - plen;
        f32x4 val;
        if ((unsigned)sl < (unsigned)SEQLEN) {
            // xk[sl][h][b][d]: flat float4 index = ((sl*NKV + h)*BATCH + b)*HD4 + d4
            val = xnew[(long long)((sl * NKV + h) * BATCH + b) * HD4 + d4];
        } else {
            val = past[rem];           // same flat offset -> perfectly coalesced
        }
        __builtin_nontemporal_store(val, &out[i]);
    }
}

extern "C" void kernel_launch(void* const* d_in, const int* in_sizes, int n_in,
                              void* d_out, int out_size, void* d_ws, size_t ws_size,
                              hipStream_t stream) {
    const f32x4* xk    = (const f32x4*)d_in[0];
    const f32x4* xv    = (const f32x4*)d_in[1];
    const f32x4* kpast = (const f32x4*)d_in[2];
    const f32x4* vpast = (const f32x4*)d_in[3];
    const int*   plen  = (const int*)d_in[4];
    f32x4*       out   = (f32x4*)d_out;

    dim3 grid(2048), block(256);   // 2048x256 = 8192 waves = exact CU co-residency
    kv_update_kernel<<<grid, block, 0, stream>>>(xk, xv, kpast, vpast, plen, out);
}